// Round 1
// baseline (890.862 us; speedup 1.0000x reference)
//
#include <hip/hip_runtime.h>
#include <stdint.h>
#include <stddef.h>

#define N_AG 81
#define HID 128
#define TROWS 128

typedef __bf16 bf16x8 __attribute__((ext_vector_type(8)));
typedef float f32x4 __attribute__((ext_vector_type(4)));
typedef uint32_t u32v4 __attribute__((ext_vector_type(4)));
typedef uint32_t u32v2 __attribute__((ext_vector_type(2)));

// s_par layout (float index)
#define PB1 0
#define PLG1 128
#define PLB1 256
#define PBN1 384
#define PMU1 512
#define PRS1 640
#define PB2 768
#define PLG2 896
#define PLB2 1024
#define PBN2 1152
#define PMU2 1280
#define PRS2 1408

__device__ __forceinline__ unsigned short f2bf(float f) {
  uint32_t u = __builtin_bit_cast(uint32_t, f);
  u += 0x7fffu + ((u >> 16) & 1u);
  return (unsigned short)(u >> 16);
}

__device__ __forceinline__ f32x4 f4z() { f32x4 v; v[0]=0.f; v[1]=0.f; v[2]=0.f; v[3]=0.f; return v; }

__device__ __forceinline__ bf16x8 ld_frag(const uint8_t* p) {
  u32v4 v = *(const u32v4*)p;
  return __builtin_bit_cast(bf16x8, v);
}

__device__ __forceinline__ f32x4 mfma16(bf16x8 a, bf16x8 b, f32x4 c) {
  return __builtin_amdgcn_mfma_f32_16x16x32_bf16(a, b, c, 0, 0, 0);
}

// in-place bias-add + layernorm over feature dim.
// acc is D^T: rows = feature o (= 16*mf + 4*g + rg), cols = batch (= 32*wv + 16*nf + q)
__device__ __forceinline__ void bias_ln(f32x4 (&acc)[8][2], const float* s_par,
                                        int PB, int PG, int PBb, int g) {
  #pragma unroll
  for (int mf = 0; mf < 8; ++mf) {
    #pragma unroll
    for (int rg = 0; rg < 4; ++rg) {
      float bo = s_par[PB + 16 * mf + 4 * g + rg];
      acc[mf][0][rg] += bo;
      acc[mf][1][rg] += bo;
    }
  }
  #pragma unroll
  for (int nf = 0; nf < 2; ++nf) {
    float s = 0.f;
    #pragma unroll
    for (int mf = 0; mf < 8; ++mf) {
      #pragma unroll
      for (int rg = 0; rg < 4; ++rg) s += acc[mf][nf][rg];
    }
    s += __shfl_xor(s, 16);
    s += __shfl_xor(s, 32);
    float mu = s * (1.f / 128.f);
    float qs = 0.f;
    #pragma unroll
    for (int mf = 0; mf < 8; ++mf) {
      #pragma unroll
      for (int rg = 0; rg < 4; ++rg) { float d = acc[mf][nf][rg] - mu; qs += d * d; }
    }
    qs += __shfl_xor(qs, 16);
    qs += __shfl_xor(qs, 32);
    float rstd = rsqrtf(qs * (1.f / 128.f) + 1e-12f);
    #pragma unroll
    for (int mf = 0; mf < 8; ++mf) {
      #pragma unroll
      for (int rg = 0; rg < 4; ++rg) {
        int o = 16 * mf + 4 * g + rg;
        acc[mf][nf][rg] = (acc[mf][nf][rg] - mu) * rstd * s_par[PG + o] + s_par[PBb + o];
      }
    }
  }
}

// per-wave BN-stat partials: sum over this wave's 32 batch cols per feature o
__device__ __forceinline__ void stats_wave(const f32x4 (&acc)[8][2],
                                           float (&s_red)[2][4][128],
                                           int wv, int g, int q) {
  #pragma unroll
  for (int mf = 0; mf < 8; ++mf) {
    #pragma unroll
    for (int rg = 0; rg < 4; ++rg) {
      float s = acc[mf][0][rg] + acc[mf][1][rg];
      float qq = acc[mf][0][rg] * acc[mf][0][rg] + acc[mf][1][rg] * acc[mf][1][rg];
      s += __shfl_xor(s, 1); s += __shfl_xor(s, 2); s += __shfl_xor(s, 4); s += __shfl_xor(s, 8);
      qq += __shfl_xor(qq, 1); qq += __shfl_xor(qq, 2); qq += __shfl_xor(qq, 4); qq += __shfl_xor(qq, 8);
      if (q == 0) {
        int o = 16 * mf + 4 * g + rg;
        s_red[0][wv][o] = s;
        s_red[1][wv][o] = qq;
      }
    }
  }
}

// Pre-transpose + bf16 + XOR-swizzle weight images (LDS-image layout).
// w1img: per agent [o=128][k=64] bf16, 128B rows; w2img: [o=128][k=128] bf16, 256B rows.
__global__ void prep_weights(const float* __restrict__ W1, const float* __restrict__ W2,
                             uint8_t* __restrict__ w1img, uint8_t* __restrict__ w2img) {
  const int a = blockIdx.x, t = threadIdx.x;
  for (int i = t; i < 128 * 64; i += 256) {
    int o = i & 127, kk = i >> 7;  // kk 0..63
    float v = (kk < 58) ? W1[((size_t)a * 58 + kk) * 128 + o] : 0.f;
    uint32_t cb = 2u * kk;
    uint32_t phys = o * 128 + (((cb & ~15u) ^ (((uint32_t)o & 7u) << 4)) | (cb & 15u));
    *(unsigned short*)(w1img + (size_t)a * 16384 + phys) = f2bf(v);
  }
  for (int i = t; i < 128 * 128; i += 256) {
    int o = i & 127, kk = i >> 7;  // kk 0..127
    float v = W2[((size_t)a * 128 + kk) * 128 + o];
    uint32_t cb = 2u * kk;
    uint32_t phys = o * 256 + (((cb & ~15u) ^ (((uint32_t)o & 7u) << 4)) | (cb & 15u));
    *(unsigned short*)(w2img + (size_t)a * 32768 + phys) = f2bf(v);
  }
}

__global__ void reduce_stats(const float* __restrict__ partS, const float* __restrict__ partQ,
                             float* __restrict__ mu, float* __restrict__ rs) {
  const int a = blockIdx.x, c = threadIdx.x;  // 128 threads
  float S = 0.f, Q = 0.f;
  for (int tb = 0; tb < 32; ++tb) {
    S += partS[((size_t)a * 32 + tb) * HID + c];
    Q += partQ[((size_t)a * 32 + tb) * HID + c];
  }
  float m = S * (1.f / 16384.f);
  float v = Q * (1.f / 16384.f) - m * m;
  mu[a * HID + c] = m;
  rs[a * HID + c] = rsqrtf(v + 1e-3f);  // BN_EPS
}

template <int PASS>
__launch_bounds__(256, 2)
__global__ void pass_kernel(
    const float* __restrict__ obs, const int* __restrict__ nidx,
    const float* __restrict__ b1, const float* __restrict__ ln1g,
    const float* __restrict__ ln1b, const float* __restrict__ bnb1,
    const float* __restrict__ b2, const float* __restrict__ ln2g,
    const float* __restrict__ ln2b, const float* __restrict__ bnb2,
    const float* __restrict__ wout, const float* __restrict__ boutp,
    const uint8_t* __restrict__ w1img, const uint8_t* __restrict__ w2img,
    const float* __restrict__ mu1, const float* __restrict__ rs1,
    const float* __restrict__ mu2, const float* __restrict__ rs2,
    float* __restrict__ partS, float* __restrict__ partQ,
    float* __restrict__ out) {
  // s_main: [0,16K) xtile [128 rows][128B]; [16K,32K) W1 image; both replaced by
  // h1T [128 rows][256B] after GEMM1. [32K,48K) W2 half image [128][128B].
  // PASS3 epilogue: [0,43008) out staging [128][84] f32.
  __shared__ __align__(16) uint8_t s_main[49152];
  __shared__ float s_par[12 * 128];
  __shared__ float s_wout[HID * 5];
  __shared__ float s_bout[8];
  __shared__ float s_red[2][4][128];

  const int t = threadIdx.x;
  const int wv = t >> 6, l = t & 63, g = l >> 4, q = l & 15;

  int a, sub, tile0, ntl;
  if constexpr (PASS == 3) {
    a = blockIdx.x >> 7; tile0 = blockIdx.x & 127; sub = 0; ntl = 1;
  } else {
    a = blockIdx.x >> 5; sub = blockIdx.x & 31; tile0 = sub * 4; ntl = 4;
  }

  const int r9 = a / 9, c9 = a - 9 * r9;
  const int deg = 1 + (r9 > 0) + (r9 < 8) + (c9 > 0) + (c9 < 8);
  int nid[5];
  #pragma unroll
  for (int d = 0; d < 5; ++d) nid[d] = nidx[a * 5 + d];

  if (t < HID) {
    s_par[PB1 + t] = b1[a * HID + t];
    s_par[PLG1 + t] = ln1g[a * HID + t];
    s_par[PLB1 + t] = ln1b[a * HID + t];
    if constexpr (PASS >= 2) {
      s_par[PBN1 + t] = bnb1[a * HID + t];
      s_par[PMU1 + t] = mu1[a * HID + t];
      s_par[PRS1 + t] = rs1[a * HID + t];
      s_par[PB2 + t] = b2[a * HID + t];
      s_par[PLG2 + t] = ln2g[a * HID + t];
      s_par[PLB2 + t] = ln2b[a * HID + t];
    }
    if constexpr (PASS == 3) {
      s_par[PBN2 + t] = bnb2[a * HID + t];
      s_par[PMU2 + t] = mu2[a * HID + t];
      s_par[PRS2 + t] = rs2[a * HID + t];
      #pragma unroll
      for (int d = 0; d < 5; ++d) s_wout[t * 5 + d] = wout[(a * HID + t) * 5 + d];
    }
  }
  if constexpr (PASS == 3) {
    if (t < 5) s_bout[t] = boutp[a * 5 + t];
  }

  float Sacc = 0.f, Qacc = 0.f;
  const uint8_t* w1src = w1img + (size_t)a * 16384;
  const uint8_t* w2src = w2img + (size_t)a * 32768;

  for (int tt = 0; tt < ntl; ++tt) {
    const int tile = tile0 + tt;

    // ---- stage: W1 image (linear), W2 half0, X tile (gather+bf16+swizzle) ----
    if (PASS != 1 || tt == 0) {
      #pragma unroll
      for (int i = 0; i < 4; ++i) {
        int idx = t + 256 * i;
        ((u32v4*)(s_main + 16384))[idx] = ((const u32v4*)w1src)[idx];
      }
    }
    if constexpr (PASS >= 2) {
      #pragma unroll
      for (int i = 0; i < 4; ++i) {
        int idx = t + 256 * i;
        int row = idx >> 3, ch = idx & 7;
        *(u32v4*)(s_main + 32768 + row * 128 + ch * 16) =
            *(const u32v4*)(w2src + row * 256 + ch * 16);
      }
    }
    {
      const int xr = t >> 1, xh = t & 1;
      const int bg = tile * TROWS + xr;
      const float* orow = obs + (size_t)bg * 210;
      #pragma unroll
      for (int jj = 0; jj < 4; ++jj) {
        unsigned short us[8];
        #pragma unroll
        for (int e = 0; e < 8; ++e) {
          const int k = 32 * xh + 8 * jj + e;
          float v;
          if (k < 5)       v = (k < deg) ? orow[48 + nid[k]] : 0.f;
          else if (k < 10) v = ((k - 5) < deg) ? orow[129 + nid[k - 5]] : 0.f;
          else if (k < 58) v = orow[k - 10];
          else             v = 0.f;
          us[e] = f2bf(v);
        }
        u32v4 pk;
        pk[0] = (uint32_t)us[0] | ((uint32_t)us[1] << 16);
        pk[1] = (uint32_t)us[2] | ((uint32_t)us[3] << 16);
        pk[2] = (uint32_t)us[4] | ((uint32_t)us[5] << 16);
        pk[3] = (uint32_t)us[6] | ((uint32_t)us[7] << 16);
        uint32_t cb = ((uint32_t)(16 * (4 * xh + jj))) ^ (((uint32_t)xr & 7u) << 4);
        *(u32v4*)(s_main + xr * 128 + cb) = pk;
      }
    }
    __syncthreads();

    // ---- GEMM1: acc1 = (X @ W1)^T  -> rows=o, cols=batch ----
    f32x4 acc1[8][2];
    #pragma unroll
    for (int mf = 0; mf < 8; ++mf) { acc1[mf][0] = f4z(); acc1[mf][1] = f4z(); }
    {
      const uint8_t* sx = s_main;
      const uint8_t* sw1 = s_main + 16384;
      const int rb = 32 * wv;
      #pragma unroll
      for (int ks = 0; ks < 2; ++ks) {
        bf16x8 bfr[2];
        #pragma unroll
        for (int nf = 0; nf < 2; ++nf) {
          uint32_t r = rb + 16 * nf + q;
          uint32_t cb = ((uint32_t)(64 * ks + 16 * g)) ^ ((r & 7u) << 4);
          bfr[nf] = ld_frag(sx + r * 128 + cb);
        }
        #pragma unroll
        for (int mf = 0; mf < 8; ++mf) {
          uint32_t r = 16 * mf + q;
          uint32_t cb = ((uint32_t)(64 * ks + 16 * g)) ^ ((r & 7u) << 4);
          bf16x8 af = ld_frag(sw1 + r * 128 + cb);
          acc1[mf][0] = mfma16(af, bfr[0], acc1[mf][0]);
          acc1[mf][1] = mfma16(af, bfr[1], acc1[mf][1]);
        }
      }
    }

    bias_ln(acc1, s_par, PB1, PLG1, PLB1, g);  // acc1 = y1 = LN1(X@W1 + b1)

    if constexpr (PASS == 1) {
      stats_wave(acc1, s_red, wv, g, q);
      __syncthreads();
      if (t < HID) {
        Sacc += s_red[0][0][t] + s_red[0][1][t] + s_red[0][2][t] + s_red[0][3][t];
        Qacc += s_red[1][0][t] + s_red[1][1][t] + s_red[1][2][t] + s_red[1][3][t];
      }
    } else {
      // ---- BN1 + ReLU, pack h1 to LDS as [batch][o] bf16 (swizzled, b64 packs) ----
      __syncthreads();  // all GEMM1 LDS reads complete before overwrite
      #pragma unroll
      for (int mf = 0; mf < 8; ++mf) {
        #pragma unroll
        for (int nf = 0; nf < 2; ++nf) {
          unsigned short us[4];
          #pragma unroll
          for (int rg = 0; rg < 4; ++rg) {
            int o = 16 * mf + 4 * g + rg;
            float z = (acc1[mf][nf][rg] - s_par[PMU1 + o]) * s_par[PRS1 + o] + s_par[PBN1 + o];
            us[rg] = f2bf(fmaxf(z, 0.f));
          }
          uint32_t b_ = 32 * wv + 16 * nf + q;
          uint32_t cb = 2u * (16 * mf + 4 * g);
          uint32_t phys = b_ * 256 + (((cb & ~15u) ^ ((b_ & 7u) << 4)) | (cb & 15u));
          u32v2 pk;
          pk[0] = (uint32_t)us[0] | ((uint32_t)us[1] << 16);
          pk[1] = (uint32_t)us[2] | ((uint32_t)us[3] << 16);
          *(u32v2*)(s_main + phys) = pk;
        }
      }
      __syncthreads();

      // ---- GEMM2: acc2 = (h1 @ W2)^T, K=128 in two staged halves ----
      f32x4 acc2[8][2];
      #pragma unroll
      for (int mf = 0; mf < 8; ++mf) { acc2[mf][0] = f4z(); acc2[mf][1] = f4z(); }
      {
        const uint8_t* sh1 = s_main;
        const uint8_t* sw2 = s_main + 32768;
        #pragma unroll
        for (int kh = 0; kh < 2; ++kh) {
          if (kh == 1) {
            __syncthreads();
            #pragma unroll
            for (int i = 0; i < 4; ++i) {
              int idx = t + 256 * i;
              int row = idx >> 3, ch = idx & 7;
              *(u32v4*)(s_main + 32768 + row * 128 + ch * 16) =
                  *(const u32v4*)(w2src + row * 256 + 128 + ch * 16);
            }
            __syncthreads();
          }
          #pragma unroll
          for (int kss = 0; kss < 2; ++kss) {
            bf16x8 bfr[2];
            #pragma unroll
            for (int nf = 0; nf < 2; ++nf) {
              uint32_t r = 32 * wv + 16 * nf + q;
              uint32_t cb = ((uint32_t)(128 * kh + 64 * kss + 16 * g)) ^ ((r & 7u) << 4);
              bfr[nf] = ld_frag(sh1 + r * 256 + cb);
            }
            #pragma unroll
            for (int mf = 0; mf < 8; ++mf) {
              uint32_t r = 16 * mf + q;
              uint32_t cb = ((uint32_t)(64 * kss + 16 * g)) ^ ((r & 7u) << 4);
              bf16x8 af = ld_frag(sw2 + r * 128 + cb);
              acc2[mf][0] = mfma16(af, bfr[0], acc2[mf][0]);
              acc2[mf][1] = mfma16(af, bfr[1], acc2[mf][1]);
            }
          }
        }
      }

      bias_ln(acc2, s_par, PB2, PLG2, PLB2, g);  // acc2 = y2 = LN2(h1@W2 + b2)

      if constexpr (PASS == 2) {
        stats_wave(acc2, s_red, wv, g, q);
        __syncthreads();
        if (t < HID) {
          Sacc += s_red[0][0][t] + s_red[0][1][t] + s_red[0][2][t] + s_red[0][3][t];
          Qacc += s_red[1][0][t] + s_red[1][1][t] + s_red[1][2][t] + s_red[1][3][t];
        }
      }

      if constexpr (PASS == 3) {
        // ---- BN2 + ReLU + GEMM3 (fp32 VALU) ----
        float lg[2][5];
        #pragma unroll
        for (int nf = 0; nf < 2; ++nf) {
          #pragma unroll
          for (int d = 0; d < 5; ++d) lg[nf][d] = 0.f;
        }
        #pragma unroll
        for (int mf = 0; mf < 8; ++mf) {
          #pragma unroll
          for (int rg = 0; rg < 4; ++rg) {
            int o = 16 * mf + 4 * g + rg;
            float m2 = s_par[PMU2 + o], r2 = s_par[PRS2 + o], bb2 = s_par[PBN2 + o];
            float h0 = fmaxf((acc2[mf][0][rg] - m2) * r2 + bb2, 0.f);
            float h1v = fmaxf((acc2[mf][1][rg] - m2) * r2 + bb2, 0.f);
            #pragma unroll
            for (int d = 0; d < 5; ++d) {
              float wvv = s_wout[o * 5 + d];
              lg[0][d] += h0 * wvv;
              lg[1][d] += h1v * wvv;
            }
          }
        }
        #pragma unroll
        for (int nf = 0; nf < 2; ++nf) {
          #pragma unroll
          for (int d = 0; d < 5; ++d) {
            float v = lg[nf][d];
            v += __shfl_xor(v, 16);
            v += __shfl_xor(v, 32);
            lg[nf][d] = v + s_bout[d];
          }
        }
        // masked softmax over d (masked slots -> exact 0)
        float p[2][5];
        #pragma unroll
        for (int nf = 0; nf < 2; ++nf) {
          float mx = lg[nf][0];
          #pragma unroll
          for (int d = 1; d < 5; ++d)
            if (d < deg) mx = fmaxf(mx, lg[nf][d]);
          float den = 0.f;
          #pragma unroll
          for (int d = 0; d < 5; ++d) {
            float e = (d < deg) ? __expf(lg[nf][d] - mx) : 0.f;
            p[nf][d] = e;
            den += e;
          }
          float inv = 1.f / den;
          #pragma unroll
          for (int d = 0; d < 5; ++d) p[nf][d] *= inv;
        }

        // ---- scatter into [128][84] staging, then coalesced store ----
        __syncthreads();  // all GEMM2 LDS reads done before overwrite
        float* s_out = (float*)s_main;
        #pragma unroll
        for (int i = 0; i < 11; ++i) {
          int idx = t + 256 * i;
          if (idx < 2688) {
            u32v4 z; z[0] = 0u; z[1] = 0u; z[2] = 0u; z[3] = 0u;
            ((u32v4*)s_out)[idx] = z;
          }
        }
        __syncthreads();
        #pragma unroll
        for (int d = 0; d < 5; ++d) {
          bool writer = (d < 4) ? (g == d) : (g == 0);
          if (writer && d < deg) {
            s_out[(32 * wv + q) * 84 + nid[d]] = p[0][d];
            s_out[(32 * wv + 16 + q) * 84 + nid[d]] = p[1][d];
          }
        }
        __syncthreads();
        const size_t obase = (size_t)(tile * TROWS) * 6561 + (size_t)a * 81;
        for (int i = t; i < 128 * 81; i += 256) {
          int r = i / 81;
          int n = i - r * 81;
          out[obase + (size_t)r * 6561 + n] = s_out[r * 84 + n];
        }
      }
    }
  }

  if constexpr (PASS != 3) {
    if (t < HID) {
      partS[((size_t)a * 32 + sub) * HID + t] = Sacc;
      partQ[((size_t)a * 32 + sub) * HID + t] = Qacc;
    }
  }
}

extern "C" void kernel_launch(void* const* d_in, const int* in_sizes, int n_in,
                              void* d_out, int out_size, void* d_ws, size_t ws_size,
                              hipStream_t stream) {
  const float* obs = (const float*)d_in[0];
  const int* nidx = (const int*)d_in[1];
  // d_in[2] = neigh_mask (derived structurally from the 9x9 grid instead)
  const float* W1 = (const float*)d_in[3];
  const float* b1 = (const float*)d_in[4];
  const float* ln1g = (const float*)d_in[5];
  const float* ln1b = (const float*)d_in[6];
  const float* bnb1 = (const float*)d_in[7];
  const float* W2 = (const float*)d_in[8];
  const float* b2 = (const float*)d_in[9];
  const float* ln2g = (const float*)d_in[10];
  const float* ln2b = (const float*)d_in[11];
  const float* bnb2 = (const float*)d_in[12];
  const float* Wout = (const float*)d_in[13];
  const float* bout = (const float*)d_in[14];
  float* out = (float*)d_out;
  uint8_t* ws = (uint8_t*)d_ws;

  uint8_t* w1img = ws;                             // 81*16384 = 1,327,104 B
  uint8_t* w2img = ws + 1327104;                   // 81*32768 = 2,654,208 B
  float* partS1 = (float*)(ws + 3981312);          // 81*32*128*4
  float* partQ1 = (float*)(ws + 5308416);
  float* partS2 = (float*)(ws + 6635520);
  float* partQ2 = (float*)(ws + 7962624);
  float* mu1 = (float*)(ws + 9289728);             // 81*128*4 each
  float* rs1 = (float*)(ws + 9331200);
  float* mu2 = (float*)(ws + 9372672);
  float* rs2 = (float*)(ws + 9414144);
  // total ws use: 9,455,616 B

  prep_weights<<<N_AG, 256, 0, stream>>>(W1, W2, w1img, w2img);

  pass_kernel<1><<<N_AG * 32, 256, 0, stream>>>(
      obs, nidx, b1, ln1g, ln1b, bnb1, b2, ln2g, ln2b, bnb2, Wout, bout,
      w1img, w2img, mu1, rs1, mu2, rs2, partS1, partQ1, out);
  reduce_stats<<<N_AG, 128, 0, stream>>>(partS1, partQ1, mu1, rs1);

  pass_kernel<2><<<N_AG * 32, 256, 0, stream>>>(
      obs, nidx, b1, ln1g, ln1b, bnb1, b2, ln2g, ln2b, bnb2, Wout, bout,
      w1img, w2img, mu1, rs1, mu2, rs2, partS2, partQ2, out);
  reduce_stats<<<N_AG, 128, 0, stream>>>(partS2, partQ2, mu2, rs2);

  pass_kernel<3><<<N_AG * 128, 256, 0, stream>>>(
      obs, nidx, b1, ln1g, ln1b, bnb1, b2, ln2g, ln2b, bnb2, Wout, bout,
      w1img, w2img, mu1, rs1, mu2, rs2, partS1, partQ1, out);
}